// Round 1
// baseline (32037.955 us; speedup 1.0000x reference)
//
#include <hip/hip_runtime.h>

// liGRU on MI355X.
// Phase 1: P[64000][2048](bf16, stored in d_out) = x @ [Wh;Wz]^T  + column sums/sumsq (f32 atomics)
// Phase 2: persistent scan kernel, 8 independent groups (4 batch rows each) of 32 WGs,
//          flag-based intra-group sync, U held in VGPRs as MFMA fragments.

#define T_STEPS 2000
#define NCOLS   2048
#define PKEEP   0.8f
#define BN_EPSF 1e-5f

typedef __attribute__((ext_vector_type(8))) short bf16x8;
typedef __attribute__((ext_vector_type(4))) float f32x4;
typedef __attribute__((ext_vector_type(4))) unsigned int u32x4;

static __device__ __forceinline__ unsigned short f2bf(float f) {
  unsigned u = __builtin_bit_cast(unsigned, f);
  unsigned r = u + 0x7FFFu + ((u >> 16) & 1u);   // RNE
  return (unsigned short)(r >> 16);
}
static __device__ __forceinline__ float bf2f(unsigned short s) {
  unsigned u = ((unsigned)s) << 16;
  return __builtin_bit_cast(float, u);
}

// ---------------- K1: convert [Wh;Wz] f32 -> bf16 ----------------
__global__ void k_convw(const float* __restrict__ Wh, const float* __restrict__ Wz,
                        unsigned short* __restrict__ Wb) {
  int i = blockIdx.x * 256 + threadIdx.x;   // float4 groups; 2048*512/4 = 262144
  int e = i * 4;
  int n = e >> 9;
  int k = e & 511;
  const float* src = (n < 1024) ? (Wh + (size_t)n * 512 + k)
                                : (Wz + (size_t)(n - 1024) * 512 + k);
  float4 v = *(const float4*)src;
  *(ushort4*)(Wb + e) = make_ushort4(f2bf(v.x), f2bf(v.y), f2bf(v.z), f2bf(v.w));
}

// ---------------- K2: GEMM  P = x @ Wb^T  (+ BN stats) ----------------
// A = x [64000][512] f32 (converted on the fly), B = Wb [2048][512] bf16.
// Tile 128x128, BK=32, 4 waves (2x2 of 64x64). P stored bf16 into d_out.
__global__ __launch_bounds__(256, 2) void k_gemm(
    const float* __restrict__ X, const unsigned short* __restrict__ Wb,
    unsigned short* __restrict__ P, float* __restrict__ sums, float* __restrict__ sumsq) {
  __shared__ __align__(16) unsigned short As[128 * 32];
  __shared__ __align__(16) unsigned short Bs[128 * 32];
  const int tid  = threadIdx.x;
  const int bm   = blockIdx.x >> 4, bn = blockIdx.x & 15;
  const int lane = tid & 63, wid = tid >> 6;
  const int wm   = wid >> 1, wn = wid & 1;
  const int lrow = lane & 15, lk = lane >> 4;

  f32x4 acc[4][4] = {};

  for (int kk = 0; kk < 512; kk += 32) {
    __syncthreads();
    // B tile via async global->LDS (wave-uniform base + lane*16)
#pragma unroll
    for (int j = 0; j < 2; ++j) {
      int c = j * 256 + wid * 64 + lane;
      int brow = c >> 2, b8 = (c & 3) * 8;
      const unsigned short* gp = Wb + (size_t)(bn * 128 + brow) * 512 + kk + b8;
      __builtin_amdgcn_global_load_lds(
          (const __attribute__((address_space(1))) unsigned int*)gp,
          (__attribute__((address_space(3))) unsigned int*)(Bs + (size_t)(j * 256 + wid * 64) * 8),
          16, 0, 0);
    }
    // A tile: f32 load -> bf16 pack -> LDS
    {
      int arow = tid >> 1, ahalf = tid & 1;
      const float4* xp = (const float4*)(X + (size_t)(bm * 128 + arow) * 512 + kk + ahalf * 16);
      unsigned v[8];
#pragma unroll
      for (int j = 0; j < 4; ++j) {
        float4 f = xp[j];
        v[j * 2 + 0] = (unsigned)f2bf(f.x) | ((unsigned)f2bf(f.y) << 16);
        v[j * 2 + 1] = (unsigned)f2bf(f.z) | ((unsigned)f2bf(f.w) << 16);
      }
      u32x4* ap = (u32x4*)(As + arow * 32 + ahalf * 16);
      u32x4 t0 = {v[0], v[1], v[2], v[3]};
      u32x4 t1 = {v[4], v[5], v[6], v[7]};
      ap[0] = t0; ap[1] = t1;
    }
    __syncthreads();

    bf16x8 af[4], bfr[4];
#pragma unroll
    for (int mt = 0; mt < 4; ++mt)
      af[mt] = *(const bf16x8*)(As + (wm * 64 + mt * 16 + lrow) * 32 + lk * 8);
#pragma unroll
    for (int nt = 0; nt < 4; ++nt)
      bfr[nt] = *(const bf16x8*)(Bs + (wn * 64 + nt * 16 + lrow) * 32 + lk * 8);
#pragma unroll
    for (int mt = 0; mt < 4; ++mt)
#pragma unroll
      for (int nt = 0; nt < 4; ++nt)
        acc[mt][nt] = __builtin_amdgcn_mfma_f32_16x16x32_bf16(af[mt], bfr[nt], acc[mt][nt], 0, 0, 0);
  }

  // epilogue: store P (bf16) ; D layout: col=lane&15, row=(lane>>4)*4+reg (m89-verified)
#pragma unroll
  for (int mt = 0; mt < 4; ++mt)
#pragma unroll
    for (int nt = 0; nt < 4; ++nt) {
      f32x4 a = acc[mt][nt];
      int gcol  = bn * 128 + wn * 64 + nt * 16 + lrow;
      int grow0 = bm * 128 + wm * 64 + mt * 16 + lk * 4;
#pragma unroll
      for (int rr = 0; rr < 4; ++rr)
        P[(size_t)(grow0 + rr) * NCOLS + gcol] = f2bf(a[rr]);
    }
  // BN stats: per-column sum / sumsq over this WG's 128 rows
#pragma unroll
  for (int nt = 0; nt < 4; ++nt) {
    float s = 0.f, q = 0.f;
#pragma unroll
    for (int mt = 0; mt < 4; ++mt) {
      f32x4 a = acc[mt][nt];
#pragma unroll
      for (int rr = 0; rr < 4; ++rr) { s += a[rr]; q += a[rr] * a[rr]; }
    }
    s += __shfl_xor(s, 16); s += __shfl_xor(s, 32);
    q += __shfl_xor(q, 16); q += __shfl_xor(q, 32);
    if (lane < 16) {
      int gcol = bn * 128 + wn * 64 + nt * 16 + lrow;
      atomicAdd(&sums[gcol], s);
      atomicAdd(&sumsq[gcol], q);
    }
  }
}

// ---------------- K4: persistent scan ----------------
// grid=256: g=blockIdx&7 (group: batch rows 4g..4g+3), r=blockIdx>>3 (units 32r..32r+31).
// waves 0,1: z-gate (Uz); waves 2,3: candidate (Uh). U fragments (x0.8) live in VGPRs.
__global__ __launch_bounds__(256, 1) void k_scan(
    const float* __restrict__ Uh, const float* __restrict__ Uz,
    const float* __restrict__ gwh, const float* __restrict__ bwh,
    const float* __restrict__ gwz, const float* __restrict__ bwz,
    const unsigned short* P,            // aliases d_out (bf16 view) -- no restrict!
    const float* __restrict__ sums, const float* __restrict__ sumsq,
    unsigned int* flags,                // [8][64]
    unsigned int* hbuf,                 // [8][2][4][512] u32 (bf16 pairs)
    float* out)                         // aliases d_out (f32 view) -- no restrict!
{
  __shared__ __align__(16) unsigned char hlds[8192];  // h_prev [4][1024] bf16, XOR-swizzled
  __shared__ __align__(16) float zlds[128];           // z exchange [32 units][4 rows]

  const int tid  = threadIdx.x;
  const int g    = blockIdx.x & 7;
  const int r    = blockIdx.x >> 3;
  const int lane = tid & 63;
  const int wid  = tid >> 6;
  const int lrow = lane & 15, lk = lane >> 4;
  const int b0   = g * 4;
  const int u0   = r * 32;
  const int uw   = u0 + (wid & 1) * 16;
  const bool isZ = (wid < 2);
  const int uu   = uw + lrow;
  const int col  = isZ ? (1024 + uu) : uu;

  // BatchNorm scale/bias for this lane's column
  float scl, bia;
  {
    float s = sums[col], q = sumsq[col];
    float gam = isZ ? gwz[uu] : gwh[uu];
    float bet = isZ ? bwz[uu] : bwh[uu];
    float mean = s * (1.0f / 64000.0f);
    float var  = q * (1.0f / 64000.0f) - mean * mean;
    float rstd = rsqrtf(var + BN_EPSF);
    scl = gam * rstd;
    bia = bet - mean * scl;
  }

  // Preload U row (x PKEEP) as 32 MFMA B-fragments -> 128 VGPRs
  const float* urow = (isZ ? Uz : Uh) + (size_t)uu * 1024;
  bf16x8 bfrag[32];
#pragma unroll
  for (int kt = 0; kt < 32; ++kt) {
    const float4* p4 = (const float4*)(urow + kt * 32 + lk * 8);
    float4 fa = p4[0], fb = p4[1];
    bf16x8 t;
    t[0] = (short)f2bf(fa.x * PKEEP); t[1] = (short)f2bf(fa.y * PKEEP);
    t[2] = (short)f2bf(fa.z * PKEEP); t[3] = (short)f2bf(fa.w * PKEEP);
    t[4] = (short)f2bf(fb.x * PKEEP); t[5] = (short)f2bf(fb.y * PKEEP);
    t[6] = (short)f2bf(fb.z * PKEEP); t[7] = (short)f2bf(fb.w * PKEEP);
    bfrag[kt] = t;
  }

  // P prefetch for t=0
  unsigned short pf[4];
#pragma unroll
  for (int rr = 0; rr < 4; ++rr)
    pf[rr] = P[(size_t)(b0 + rr) * NCOLS + col];

  f32x4 hown = {0.f, 0.f, 0.f, 0.f};
  unsigned int* flg = flags + g * 64;

  for (int t = 0; t < T_STEPS; ++t) {
    // 1. wait: all 64 producer flags of this group reached t
    {
      const unsigned int* fp = flg + lane;
      while (true) {
        unsigned int f = __hip_atomic_load(fp, __ATOMIC_RELAXED, __HIP_MEMORY_SCOPE_SYSTEM);
        if (__all((int)(f >= (unsigned)t))) break;
        __builtin_amdgcn_s_sleep(2);
      }
    }
    __builtin_amdgcn_fence(__ATOMIC_ACQUIRE, "workgroup");  // order spin-exit vs data loads

    // 2. h_prev (group buffer t&1) -> LDS, XOR-swizzled
    {
      const unsigned int* hb = hbuf + (size_t)(g * 2 + (t & 1)) * 2048;
#pragma unroll
      for (int j = 0; j < 2; ++j) {
        int c = tid + j * 256;           // 16B chunk id, 512 total
        int row = c >> 7;
        unsigned v0 = __hip_atomic_load(hb + c * 4 + 0, __ATOMIC_RELAXED, __HIP_MEMORY_SCOPE_SYSTEM);
        unsigned v1 = __hip_atomic_load(hb + c * 4 + 1, __ATOMIC_RELAXED, __HIP_MEMORY_SCOPE_SYSTEM);
        unsigned v2 = __hip_atomic_load(hb + c * 4 + 2, __ATOMIC_RELAXED, __HIP_MEMORY_SCOPE_SYSTEM);
        unsigned v3 = __hip_atomic_load(hb + c * 4 + 3, __ATOMIC_RELAXED, __HIP_MEMORY_SCOPE_SYSTEM);
        int byteoff = (c * 16) ^ ((row & 3) << 5);
        u32x4 tv = {v0, v1, v2, v3};
        *(u32x4*)(hlds + byteoff) = tv;
      }
    }
    __syncthreads();  // B1: hlds ready (drains vmcnt too)

    // 3. prefetch P for t+1 (drained by B2's vmcnt(0) -> safe vs out[t+1] overwrite)
    unsigned short pn[4] = {pf[0], pf[1], pf[2], pf[3]};
    if (t + 1 < T_STEPS) {
#pragma unroll
      for (int rr = 0; rr < 4; ++rr)
        pn[rr] = P[(size_t)((t + 1) * 32 + b0 + rr) * NCOLS + col];
    }

    // 4. dot: (h*0.8) @ U_slice^T ; 4 partial accumulators for MFMA ILP
    f32x4 ac0 = {0.f, 0.f, 0.f, 0.f}, ac1 = ac0, ac2 = ac0, ac3 = ac0;
#pragma unroll
    for (int kt = 0; kt < 32; ++kt) {
      int ab = (((lane & 3) * 2048) + kt * 64 + lk * 16) ^ ((lane & 3) << 5);
      bf16x8 af = *(const bf16x8*)(hlds + ab);
      if ((kt & 3) == 0)      ac0 = __builtin_amdgcn_mfma_f32_16x16x32_bf16(af, bfrag[kt], ac0, 0, 0, 0);
      else if ((kt & 3) == 1) ac1 = __builtin_amdgcn_mfma_f32_16x16x32_bf16(af, bfrag[kt], ac1, 0, 0, 0);
      else if ((kt & 3) == 2) ac2 = __builtin_amdgcn_mfma_f32_16x16x32_bf16(af, bfrag[kt], ac2, 0, 0, 0);
      else                    ac3 = __builtin_amdgcn_mfma_f32_16x16x32_bf16(af, bfrag[kt], ac3, 0, 0, 0);
    }
    f32x4 dsum = (ac0 + ac1) + (ac2 + ac3);

    // 5. pre-activation = dot + BN(P)   (valid in lanes 0..15, regs = batch rows 0..3)
    float pre[4];
#pragma unroll
    for (int rr = 0; rr < 4; ++rr)
      pre[rr] = dsum[rr] + bf2f(pf[rr]) * scl + bia;

    if (isZ && lane < 16) {
      f32x4 zv;
#pragma unroll
      for (int rr = 0; rr < 4; ++rr) zv[rr] = 1.0f / (1.0f + __expf(-pre[rr]));
      *(f32x4*)(zlds + ((wid & 1) * 16 + lrow) * 4) = zv;
    }
    __syncthreads();  // B2: z published; drains ALL waves' vmcnt (incl. P prefetch)

    if (!isZ && lane < 16) {
      f32x4 zv = *(const f32x4*)(zlds + ((wid & 1) * 16 + lrow) * 4);
      f32x4 hn;
#pragma unroll
      for (int rr = 0; rr < 4; ++rr) {
        float hc = fmaxf(pre[rr], 0.0f) * PKEEP;        // relu * 'orig' dropout scale
        hn[rr] = zv[rr] * hown[rr] + (1.0f - zv[rr]) * hc;
      }
      hown = hn;
#pragma unroll
      for (int rr = 0; rr < 4; ++rr)
        out[(size_t)(t * 32 + b0 + rr) * 1024 + uu] = hn[rr];
      // publish h_new (bf16 pairs) to group buffer (t+1)&1
      unsigned int* hbn = hbuf + (size_t)(g * 2 + ((t + 1) & 1)) * 2048;
#pragma unroll
      for (int rr = 0; rr < 4; ++rr) {
        float o = __shfl_xor(hn[rr], 1);
        if ((lane & 1) == 0) {
          unsigned int pk = (unsigned)f2bf(hn[rr]) | ((unsigned)f2bf(o) << 16);
          __hip_atomic_store(hbn + rr * 512 + (uu >> 1), pk,
                             __ATOMIC_RELAXED, __HIP_MEMORY_SCOPE_SYSTEM);
        }
      }
    }
    if (!isZ && lane == 0)
      __hip_atomic_store(flg + r * 2 + (wid - 2), (unsigned)(t + 1),
                         __ATOMIC_RELEASE, __HIP_MEMORY_SCOPE_SYSTEM);

#pragma unroll
    for (int rr = 0; rr < 4; ++rr) pf[rr] = pn[rr];
  }
}

// ---------------- launch ----------------
extern "C" void kernel_launch(void* const* d_in, const int* in_sizes, int n_in,
                              void* d_out, int out_size, void* d_ws, size_t ws_size,
                              hipStream_t stream) {
  (void)in_sizes; (void)n_in; (void)out_size; (void)ws_size;
  const float* x   = (const float*)d_in[0];
  const float* Wh  = (const float*)d_in[1];
  const float* Wz  = (const float*)d_in[2];
  const float* Uh  = (const float*)d_in[3];
  const float* Uz  = (const float*)d_in[4];
  const float* gwh = (const float*)d_in[5];
  const float* bwh = (const float*)d_in[6];
  const float* gwz = (const float*)d_in[7];
  const float* bwz = (const float*)d_in[8];

  char* ws = (char*)d_ws;
  unsigned int*   flags = (unsigned int*)(ws + 0);       // 2048 B
  float*          sums  = (float*)(ws + 2048);           // 8192 B
  float*          sumsq = (float*)(ws + 10240);          // 8192 B
  unsigned int*   hbuf  = (unsigned int*)(ws + 18432);   // 131072 B
  unsigned short* Wb    = (unsigned short*)(ws + 151552);// 2 MiB

  // zero flags + stats + h buffers every call (graph-replay safe)
  hipMemsetAsync(d_ws, 0, 149504, stream);
  k_convw<<<1024, 256, 0, stream>>>(Wh, Wz, Wb);
  // P (bf16) lives in d_out; scan overwrites it with f32 output in provably-ordered fashion
  k_gemm<<<8000, 256, 0, stream>>>(x, Wb, (unsigned short*)d_out, sums, sumsq);
  k_scan<<<256, 256, 0, stream>>>(Uh, Uz, gwh, bwh, gwz, bwz,
                                  (const unsigned short*)d_out, sums, sumsq,
                                  flags, hbuf, (float*)d_out);
}

// Round 2
// 7258.143 us; speedup vs baseline: 4.4141x; 4.4141x over previous
//
#include <hip/hip_runtime.h>

// liGRU on MI355X.
// Phase 1: P[64000][2048](bf16, stored in d_out) = x @ [Wh;Wz]^T  + column sums/sumsq (f32 atomics)
// Phase 2: persistent scan, 8 independent groups (4 batch rows each) of 32 WGs.
//          Sync via 8-byte atomic records {tag(hi32) | 2xbf16 h (lo32)} -- flag IS the data:
//          no release fences, no wbl2, no producer ack wait, single L3 one-way per step.

#define T_STEPS 2000
#define NCOLS   2048
#define PKEEP   0.8f
#define BN_EPSF 1e-5f

typedef __attribute__((ext_vector_type(8))) short bf16x8;
typedef __attribute__((ext_vector_type(4))) float f32x4;
typedef __attribute__((ext_vector_type(4))) unsigned int u32x4;

static __device__ __forceinline__ unsigned short f2bf(float f) {
  unsigned u = __builtin_bit_cast(unsigned, f);
  unsigned r = u + 0x7FFFu + ((u >> 16) & 1u);   // RNE
  return (unsigned short)(r >> 16);
}
static __device__ __forceinline__ float bf2f(unsigned short s) {
  unsigned u = ((unsigned)s) << 16;
  return __builtin_bit_cast(float, u);
}

// ---------------- K1: convert [Wh;Wz] f32 -> bf16 ----------------
__global__ void k_convw(const float* __restrict__ Wh, const float* __restrict__ Wz,
                        unsigned short* __restrict__ Wb) {
  int i = blockIdx.x * 256 + threadIdx.x;   // float4 groups; 2048*512/4 = 262144
  int e = i * 4;
  int n = e >> 9;
  int k = e & 511;
  const float* src = (n < 1024) ? (Wh + (size_t)n * 512 + k)
                                : (Wz + (size_t)(n - 1024) * 512 + k);
  float4 v = *(const float4*)src;
  *(ushort4*)(Wb + e) = make_ushort4(f2bf(v.x), f2bf(v.y), f2bf(v.z), f2bf(v.w));
}

// ---------------- K2: GEMM  P = x @ Wb^T  (+ BN stats) ----------------
__global__ __launch_bounds__(256, 2) void k_gemm(
    const float* __restrict__ X, const unsigned short* __restrict__ Wb,
    unsigned short* __restrict__ P, float* __restrict__ sums, float* __restrict__ sumsq) {
  __shared__ __align__(16) unsigned short As[128 * 32];
  __shared__ __align__(16) unsigned short Bs[128 * 32];
  const int tid  = threadIdx.x;
  const int bm   = blockIdx.x >> 4, bn = blockIdx.x & 15;
  const int lane = tid & 63, wid = tid >> 6;
  const int wm   = wid >> 1, wn = wid & 1;
  const int lrow = lane & 15, lk = lane >> 4;

  f32x4 acc[4][4] = {};

  for (int kk = 0; kk < 512; kk += 32) {
    __syncthreads();
#pragma unroll
    for (int j = 0; j < 2; ++j) {
      int c = j * 256 + wid * 64 + lane;
      int brow = c >> 2, b8 = (c & 3) * 8;
      const unsigned short* gp = Wb + (size_t)(bn * 128 + brow) * 512 + kk + b8;
      __builtin_amdgcn_global_load_lds(
          (const __attribute__((address_space(1))) unsigned int*)gp,
          (__attribute__((address_space(3))) unsigned int*)(Bs + (size_t)(j * 256 + wid * 64) * 8),
          16, 0, 0);
    }
    {
      int arow = tid >> 1, ahalf = tid & 1;
      const float4* xp = (const float4*)(X + (size_t)(bm * 128 + arow) * 512 + kk + ahalf * 16);
      unsigned v[8];
#pragma unroll
      for (int j = 0; j < 4; ++j) {
        float4 f = xp[j];
        v[j * 2 + 0] = (unsigned)f2bf(f.x) | ((unsigned)f2bf(f.y) << 16);
        v[j * 2 + 1] = (unsigned)f2bf(f.z) | ((unsigned)f2bf(f.w) << 16);
      }
      u32x4* ap = (u32x4*)(As + arow * 32 + ahalf * 16);
      u32x4 t0 = {v[0], v[1], v[2], v[3]};
      u32x4 t1 = {v[4], v[5], v[6], v[7]};
      ap[0] = t0; ap[1] = t1;
    }
    __syncthreads();

    bf16x8 af[4], bfr[4];
#pragma unroll
    for (int mt = 0; mt < 4; ++mt)
      af[mt] = *(const bf16x8*)(As + (wm * 64 + mt * 16 + lrow) * 32 + lk * 8);
#pragma unroll
    for (int nt = 0; nt < 4; ++nt)
      bfr[nt] = *(const bf16x8*)(Bs + (wn * 64 + nt * 16 + lrow) * 32 + lk * 8);
#pragma unroll
    for (int mt = 0; mt < 4; ++mt)
#pragma unroll
      for (int nt = 0; nt < 4; ++nt)
        acc[mt][nt] = __builtin_amdgcn_mfma_f32_16x16x32_bf16(af[mt], bfr[nt], acc[mt][nt], 0, 0, 0);
  }

#pragma unroll
  for (int mt = 0; mt < 4; ++mt)
#pragma unroll
    for (int nt = 0; nt < 4; ++nt) {
      f32x4 a = acc[mt][nt];
      int gcol  = bn * 128 + wn * 64 + nt * 16 + lrow;
      int grow0 = bm * 128 + wm * 64 + mt * 16 + lk * 4;
#pragma unroll
      for (int rr = 0; rr < 4; ++rr)
        P[(size_t)(grow0 + rr) * NCOLS + gcol] = f2bf(a[rr]);
    }
#pragma unroll
  for (int nt = 0; nt < 4; ++nt) {
    float s = 0.f, q = 0.f;
#pragma unroll
    for (int mt = 0; mt < 4; ++mt) {
      f32x4 a = acc[mt][nt];
#pragma unroll
      for (int rr = 0; rr < 4; ++rr) { s += a[rr]; q += a[rr] * a[rr]; }
    }
    s += __shfl_xor(s, 16); s += __shfl_xor(s, 32);
    q += __shfl_xor(q, 16); q += __shfl_xor(q, 32);
    if (lane < 16) {
      int gcol = bn * 128 + wn * 64 + nt * 16 + lrow;
      atomicAdd(&sums[gcol], s);
      atomicAdd(&sumsq[gcol], q);
    }
  }
}

// ---------------- K3: persistent scan ----------------
// grid=256: g=blockIdx&7 (group: batch rows 4g..4g+3), r=blockIdx>>3 (units 32r..32r+31).
// waves 0,1: z-gate (Uz); waves 2,3: candidate (Uh). U fragments (x0.8) live in VGPRs.
// h exchange: hrec[g][parity][row*512+up] = u64{ tag=t+1 (hi) | bf16 h[2up],h[2up+1] (lo) }.
__global__ __launch_bounds__(256, 1) void k_scan(
    const float* __restrict__ Uh, const float* __restrict__ Uz,
    const float* __restrict__ gwh, const float* __restrict__ bwh,
    const float* __restrict__ gwz, const float* __restrict__ bwz,
    const unsigned short* P,            // aliases d_out (bf16 view) -- no restrict!
    const float* __restrict__ sums, const float* __restrict__ sumsq,
    unsigned long long* hrec,           // [8][2][2048] u64 records
    float* out)                         // aliases d_out (f32 view) -- no restrict!
{
  __shared__ __align__(16) unsigned char hlds[8192];  // h_prev [4][1024] bf16, XOR-swizzled
  __shared__ __align__(16) float zlds[128];           // z exchange [32 units][4 rows]

  const int tid  = threadIdx.x;
  const int g    = blockIdx.x & 7;
  const int r    = blockIdx.x >> 3;
  const int lane = tid & 63;
  const int wid  = tid >> 6;
  const int lrow = lane & 15, lk = lane >> 4;
  const int b0   = g * 4;
  const int u0   = r * 32;
  const int uw   = u0 + (wid & 1) * 16;
  const bool isZ = (wid < 2);
  const int uu   = uw + lrow;
  const int col  = isZ ? (1024 + uu) : uu;

  // BatchNorm scale/bias for this lane's column
  float scl, bia;
  {
    float s = sums[col], q = sumsq[col];
    float gam = isZ ? gwz[uu] : gwh[uu];
    float bet = isZ ? bwz[uu] : bwh[uu];
    float mean = s * (1.0f / 64000.0f);
    float var  = q * (1.0f / 64000.0f) - mean * mean;
    float rstd = rsqrtf(var + BN_EPSF);
    scl = gam * rstd;
    bia = bet - mean * scl;
  }

  // Preload U row (x PKEEP) as 32 MFMA B-fragments -> 128 VGPRs
  const float* urow = (isZ ? Uz : Uh) + (size_t)uu * 1024;
  bf16x8 bfrag[32];
#pragma unroll
  for (int kt = 0; kt < 32; ++kt) {
    const float4* p4 = (const float4*)(urow + kt * 32 + lk * 8);
    float4 fa = p4[0], fb = p4[1];
    bf16x8 t;
    t[0] = (short)f2bf(fa.x * PKEEP); t[1] = (short)f2bf(fa.y * PKEEP);
    t[2] = (short)f2bf(fa.z * PKEEP); t[3] = (short)f2bf(fa.w * PKEEP);
    t[4] = (short)f2bf(fb.x * PKEEP); t[5] = (short)f2bf(fb.y * PKEEP);
    t[6] = (short)f2bf(fb.z * PKEEP); t[7] = (short)f2bf(fb.w * PKEEP);
    bfrag[kt] = t;
  }

  // P prefetch for t=0
  unsigned short pf[4];
#pragma unroll
  for (int rr = 0; rr < 4; ++rr)
    pf[rr] = P[(size_t)(b0 + rr) * NCOLS + col];

  f32x4 hown = {0.f, 0.f, 0.f, 0.f};

  for (int t = 0; t < T_STEPS; ++t) {
    // 1. poll this thread's 8 records (parity t&1) until tag >= t, data rides with tag
    unsigned long long rec[8];
    {
      const unsigned long long* rb = hrec + (((size_t)(g * 2 + (t & 1))) << 11);
#pragma unroll
      for (int j = 0; j < 8; ++j)
        rec[j] = __hip_atomic_load(rb + tid + 256 * j, __ATOMIC_RELAXED, __HIP_MEMORY_SCOPE_SYSTEM);
      while (true) {
        unsigned bad = 0;
#pragma unroll
        for (int j = 0; j < 8; ++j)
          if ((unsigned)(rec[j] >> 32) < (unsigned)t) bad |= (1u << j);
        if (!bad) break;
        __builtin_amdgcn_s_sleep(1);
#pragma unroll
        for (int j = 0; j < 8; ++j)
          if (bad & (1u << j))
            rec[j] = __hip_atomic_load(rb + tid + 256 * j, __ATOMIC_RELAXED, __HIP_MEMORY_SCOPE_SYSTEM);
      }
      // 2. unpack to LDS (XOR-swizzled); idx=tid+256j -> bank-conflict-free ds_write
#pragma unroll
      for (int j = 0; j < 8; ++j) {
        int idx = tid + 256 * j;
        int row = idx >> 9, up = idx & 511;
        int byteoff = (row * 2048 + up * 4) ^ ((row & 3) << 5);
        *(unsigned*)(hlds + byteoff) = (unsigned)rec[j];
      }
    }
    __syncthreads();  // B1: hlds ready

    // 3. prefetch P for t+1 (drained by B2's vmcnt(0) -> safe vs out[t+1] overwrite)
    unsigned short pn[4] = {pf[0], pf[1], pf[2], pf[3]};
    if (t + 1 < T_STEPS) {
#pragma unroll
      for (int rr = 0; rr < 4; ++rr)
        pn[rr] = P[(size_t)((t + 1) * 32 + b0 + rr) * NCOLS + col];
    }

    // 4. dot: (h*0.8) @ U_slice^T ; 4 partial accumulators for MFMA ILP
    f32x4 ac0 = {0.f, 0.f, 0.f, 0.f}, ac1 = ac0, ac2 = ac0, ac3 = ac0;
#pragma unroll
    for (int kt = 0; kt < 32; ++kt) {
      int ab = (((lane & 3) * 2048) + kt * 64 + lk * 16) ^ ((lane & 3) << 5);
      bf16x8 af = *(const bf16x8*)(hlds + ab);
      if ((kt & 3) == 0)      ac0 = __builtin_amdgcn_mfma_f32_16x16x32_bf16(af, bfrag[kt], ac0, 0, 0, 0);
      else if ((kt & 3) == 1) ac1 = __builtin_amdgcn_mfma_f32_16x16x32_bf16(af, bfrag[kt], ac1, 0, 0, 0);
      else if ((kt & 3) == 2) ac2 = __builtin_amdgcn_mfma_f32_16x16x32_bf16(af, bfrag[kt], ac2, 0, 0, 0);
      else                    ac3 = __builtin_amdgcn_mfma_f32_16x16x32_bf16(af, bfrag[kt], ac3, 0, 0, 0);
    }
    f32x4 dsum = (ac0 + ac1) + (ac2 + ac3);

    // 5. pre-activation = dot + BN(P)   (valid in lanes 0..15, regs = batch rows 0..3)
    float pre[4];
#pragma unroll
    for (int rr = 0; rr < 4; ++rr)
      pre[rr] = dsum[rr] + bf2f(pf[rr]) * scl + bia;

    if (isZ && lane < 16) {
      f32x4 zv;
#pragma unroll
      for (int rr = 0; rr < 4; ++rr) zv[rr] = 1.0f / (1.0f + __expf(-pre[rr]));
      *(f32x4*)(zlds + ((wid & 1) * 16 + lrow) * 4) = zv;
    }
    __syncthreads();  // B2: z published; drains ALL waves' vmcnt (incl. P prefetch)

    if (!isZ && lane < 16) {
      f32x4 zv = *(const f32x4*)(zlds + ((wid & 1) * 16 + lrow) * 4);
      f32x4 hn;
#pragma unroll
      for (int rr = 0; rr < 4; ++rr) {
        float hc = fmaxf(pre[rr], 0.0f) * PKEEP;        // relu * 'orig' dropout scale
        hn[rr] = zv[rr] * hown[rr] + (1.0f - zv[rr]) * hc;
      }
      hown = hn;
      float o[4];
#pragma unroll
      for (int rr = 0; rr < 4; ++rr) o[rr] = __shfl_xor(hn[rr], 1);
      if ((lane & 1) == 0) {
        unsigned long long* hbn = hrec + (((size_t)(g * 2 + ((t + 1) & 1))) << 11);
        unsigned tagw = (unsigned)(t + 1);
#pragma unroll
        for (int rr = 0; rr < 4; ++rr) {
          float2 ov = {hn[rr], o[rr]};
          *(float2*)(out + (size_t)(t * 32 + b0 + rr) * 1024 + uu) = ov;
          unsigned long long rcd = ((unsigned long long)tagw << 32)
                                 | (unsigned)f2bf(hn[rr]) | ((unsigned)f2bf(o[rr]) << 16);
          __hip_atomic_store(hbn + rr * 512 + (uu >> 1), rcd,
                             __ATOMIC_RELAXED, __HIP_MEMORY_SCOPE_SYSTEM);
        }
      }
    }

#pragma unroll
    for (int rr = 0; rr < 4; ++rr) pf[rr] = pn[rr];
  }
}

// ---------------- launch ----------------
extern "C" void kernel_launch(void* const* d_in, const int* in_sizes, int n_in,
                              void* d_out, int out_size, void* d_ws, size_t ws_size,
                              hipStream_t stream) {
  (void)in_sizes; (void)n_in; (void)out_size; (void)ws_size;
  const float* x   = (const float*)d_in[0];
  const float* Wh  = (const float*)d_in[1];
  const float* Wz  = (const float*)d_in[2];
  const float* Uh  = (const float*)d_in[3];
  const float* Uz  = (const float*)d_in[4];
  const float* gwh = (const float*)d_in[5];
  const float* bwh = (const float*)d_in[6];
  const float* gwz = (const float*)d_in[7];
  const float* bwz = (const float*)d_in[8];

  char* ws = (char*)d_ws;
  float*              sums  = (float*)(ws + 0);                  // 8192 B
  float*              sumsq = (float*)(ws + 8192);               // 8192 B
  unsigned long long* hrec  = (unsigned long long*)(ws + 16384); // 262144 B
  unsigned short*     Wb    = (unsigned short*)(ws + 278528);    // 2 MiB

  // zero stats + records every call (graph-replay safe; tag=0 == valid h0=0)
  hipMemsetAsync(d_ws, 0, 278528, stream);
  k_convw<<<1024, 256, 0, stream>>>(Wh, Wz, Wb);
  // P (bf16) lives in d_out; scan overwrites it with f32 output in provably-ordered fashion
  k_gemm<<<8000, 256, 0, stream>>>(x, Wb, (unsigned short*)d_out, sums, sumsq);
  k_scan<<<256, 256, 0, stream>>>(Uh, Uz, gwh, bwh, gwz, bwz,
                                  (const unsigned short*)d_out, sums, sumsq,
                                  hrec, (float*)d_out);
}